// Round 1
// baseline (23470.352 us; speedup 1.0000x reference)
//
#include <hip/hip_runtime.h>
#include <hip/hip_bf16.h>
#include <cstdint>
#include <cstddef>

#define DEV __device__ __forceinline__

DEV float sigmoidf_(float x) { return 1.0f / (1.0f + __expf(-x)); }
DEV float tanhf_(float x) {
    // tanh(x) = 1 - 2/(exp(2x)+1); stable at +/-inf of exp
    float e = __expf(2.0f * x);
    return 1.0f - 2.0f / (e + 1.0f);
}

// ---------------------------------------------------------------------------
// Input projection: xg[b,t,g] = bias[g] + sum_i (x[b,t,i] + gate?[b,t]) * Wih[g,i]
// Block: 256 threads = one gate each; 16 time steps per block staged in LDS.
// ---------------------------------------------------------------------------
__global__ __launch_bounds__(256) void proj_kernel(
    const float* __restrict__ x, const float* __restrict__ Wih,
    const float* __restrict__ bias, const float* __restrict__ gate,
    float* __restrict__ xg, int D, int T)
{
    __shared__ float xS[16 * 64];
    int tb = T / 16;
    int b  = blockIdx.x / tb;
    int t0 = (blockIdx.x % tb) * 16;
    int tid = threadIdx.x;

    int n = 16 * D;
    for (int e = tid; e < n; e += 256) {
        int t = e / D;
        int i = e - t * D;
        float v = x[((size_t)(b * T + t0 + t)) * D + i];
        if (gate) v += gate[b * T + t0 + t];   // Hp = H + sigmoid-gate (broadcast over hidden dim)
        xS[t * D + i] = v;
    }
    __syncthreads();

    int g = tid;
    float acc[16];
    float bg = bias[g];
#pragma unroll
    for (int t = 0; t < 16; t++) acc[t] = bg;

    const float* wr = Wih + (size_t)g * D;
    for (int i = 0; i < D; i++) {
        float w = wr[i];
#pragma unroll
        for (int t = 0; t < 16; t++) acc[t] += xS[t * D + i] * w;
    }

    float* og = xg + ((size_t)(b * T + t0)) * 256 + g;
#pragma unroll
    for (int t = 0; t < 16; t++) og[(size_t)t * 256] = acc[t];
}

// ---------------------------------------------------------------------------
// Persistent LSTM scan for one layer. Grid = B blocks (one per batch element),
// 256 threads: thread g owns gate row g (Whh[g,:] in 64 VGPRs). h broadcast
// from LDS; gate pre-activations exchanged via LDS; c lives in regs of lanes<64.
// Gate order (torch): i, f, g, o in blocks of 64.
// ---------------------------------------------------------------------------
__global__ __launch_bounds__(256) void scan_kernel(
    const float* __restrict__ xg, const float* __restrict__ Whh,
    const float* __restrict__ h0, const float* __restrict__ c0,
    float* __restrict__ Hout, int T)
{
    __shared__ float hS[64];
    __shared__ float gS[256];
    int b = blockIdx.x;
    int g = threadIdx.x;

    float4 w4[16];
    const float4* wp = (const float4*)(Whh + (size_t)g * 64);
#pragma unroll
    for (int q = 0; q < 16; q++) w4[q] = wp[q];

    float c = 0.f;
    if (g < 64) {
        c = c0[b * 64 + g];
        hS[g] = h0[b * 64 + g];
    }
    __syncthreads();

    const float* xp = xg + (size_t)b * T * 256 + g;
    float xn = xp[0];

    for (int t = 0; t < T; t++) {
        float a0 = xn, a1 = 0.f, a2 = 0.f, a3 = 0.f;
        if (t + 1 < T) xn = xp[(size_t)(t + 1) * 256];  // prefetch next step's xg

        const float4* hv = (const float4*)hS;
#pragma unroll
        for (int q = 0; q < 16; q++) {
            float4 h4 = hv[q];
            float4 w = w4[q];
            a0 += h4.x * w.x;
            a1 += h4.y * w.y;
            a2 += h4.z * w.z;
            a3 += h4.w * w.w;
        }
        gS[g] = (a0 + a1) + (a2 + a3);
        __syncthreads();

        if (g < 64) {
            float gi = gS[g], gf = gS[64 + g], gg = gS[128 + g], go = gS[192 + g];
            c = sigmoidf_(gf) * c + sigmoidf_(gi) * tanhf_(gg);
            float h = sigmoidf_(go) * tanhf_(c);
            hS[g] = h;
            Hout[((size_t)b * T + t) * 64 + g] = h;
        }
        __syncthreads();
    }
}

// ---------------------------------------------------------------------------
// Hc[b, {max,mean,std(ddof=1)}, t] over hidden dim (64). One wave per (b,t).
// ---------------------------------------------------------------------------
__global__ __launch_bounds__(256) void stats_kernel(
    const float* __restrict__ H, float* __restrict__ Hc, int T)
{
    int wid = threadIdx.x >> 6, lane = threadIdx.x & 63;
    int bt = blockIdx.x * 4 + wid;   // enumerates b*T+t
    int b = bt / T, t = bt - b * T;

    float x = H[(size_t)bt * 64 + lane];
    float mx = x, sm = x;
#pragma unroll
    for (int m = 32; m >= 1; m >>= 1) {
        mx = fmaxf(mx, __shfl_xor(mx, m));
        sm += __shfl_xor(sm, m);
    }
    float mean = sm * (1.0f / 64.0f);
    float d = x - mean;
    float ss = d * d;
#pragma unroll
    for (int m = 32; m >= 1; m >>= 1) ss += __shfl_xor(ss, m);
    float sd = sqrtf(ss * (1.0f / 63.0f));

    if (lane == 0) {
        float* o = Hc + (size_t)b * 3 * T;
        o[0 * T + t] = mx;
        o[1 * T + t] = mean;
        o[2 * T + t] = sd;
    }
}

// ---------------------------------------------------------------------------
// Middle conv/BN chain, single workgroup (1024 threads) so BN batch stats can
// use in-block barriers. MODE 0 = relu; MODE 1 = sigmoid -> gate (COUT must be 1).
// ---------------------------------------------------------------------------
template <int CIN, int COUT, int MODE>
DEV void conv_bn_stage(const float* __restrict__ in, const float* __restrict__ w,
                       const float* __restrict__ bias, float* __restrict__ out,
                       float* __restrict__ gate, int T, int tid,
                       float* rs, float* rq, float* stm, float* sti)
{
    float lsum[COUT], lss[COUT];
#pragma unroll
    for (int oc = 0; oc < COUT; oc++) { lsum[oc] = 0.f; lss[oc] = 0.f; }

    for (int k = 0; k < 8; k++) {
        int p = tid + k * 1024;          // enumerates b*T+t over 2*T positions
        int b = p / T;
        int t = p - b * T;
        float acc[COUT];
#pragma unroll
        for (int oc = 0; oc < COUT; oc++) acc[oc] = bias[oc];
#pragma unroll
        for (int ic = 0; ic < CIN; ic++) {
            const float* row = in + ((size_t)b * CIN + ic) * T;
            float xv[11];
#pragma unroll
            for (int kk = 0; kk < 11; kk++) {
                int tt = t + kk - 5;
                xv[kk] = (tt >= 0 && tt < T) ? row[tt] : 0.f;
            }
#pragma unroll
            for (int oc = 0; oc < COUT; oc++) {
                const float* wr = w + ((size_t)oc * CIN + ic) * 11;
#pragma unroll
                for (int kk = 0; kk < 11; kk++) acc[oc] += xv[kk] * wr[kk];
            }
        }
#pragma unroll
        for (int oc = 0; oc < COUT; oc++) {
            out[((size_t)b * COUT + oc) * T + t] = acc[oc];
            lsum[oc] += acc[oc];
            lss[oc] += acc[oc] * acc[oc];
        }
    }
    __syncthreads();

    int lane = tid & 63, wid = tid >> 6;
#pragma unroll
    for (int oc = 0; oc < COUT; oc++) {
        float s = lsum[oc], q = lss[oc];
#pragma unroll
        for (int m = 32; m >= 1; m >>= 1) {
            s += __shfl_xor(s, m);
            q += __shfl_xor(q, m);
        }
        if (lane == 0) { rs[wid] = s; rq[wid] = q; }
        __syncthreads();
        if (tid == 0) {
            float S = 0.f, Q = 0.f;
            for (int i = 0; i < 16; i++) { S += rs[i]; Q += rq[i]; }
            float m_ = S / (float)(2 * T);
            float v = Q / (float)(2 * T) - m_ * m_;   // biased var (jnp.var default)
            stm[oc] = m_;
            sti[oc] = rsqrtf(v + 1e-5f);
        }
        __syncthreads();
    }

    for (int k = 0; k < 8; k++) {
        int p = tid + k * 1024;
        int b = p / T;
        int t = p - b * T;
#pragma unroll
        for (int oc = 0; oc < COUT; oc++) {
            size_t idx = ((size_t)b * COUT + oc) * T + t;
            float v = (out[idx] - stm[oc]) * sti[oc];
            if (MODE == 0) out[idx] = fmaxf(v, 0.f);
            else           gate[p] = sigmoidf_(v);
        }
    }
    __syncthreads();
}

__global__ __launch_bounds__(1024) void middle_kernel(
    const float* __restrict__ Hc,
    const float* __restrict__ w1, const float* __restrict__ b1,
    const float* __restrict__ w2, const float* __restrict__ b2,
    const float* __restrict__ w3, const float* __restrict__ b3,
    const float* __restrict__ w4, const float* __restrict__ b4,
    float* __restrict__ bufA, float* __restrict__ bufB,
    float* __restrict__ gate, int T)
{
    __shared__ float rs[16], rq[16], stm[8], sti[8];
    int tid = threadIdx.x;
    conv_bn_stage<3, 3, 0>(Hc,   w1, b1, bufA, nullptr, T, tid, rs, rq, stm, sti);
    conv_bn_stage<3, 5, 0>(bufA, w2, b2, bufB, nullptr, T, tid, rs, rq, stm, sti);
    conv_bn_stage<5, 5, 0>(bufB, w3, b3, bufA, nullptr, T, tid, rs, rq, stm, sti);
    conv_bn_stage<5, 1, 1>(bufA, w4, b4, bufB, gate,    T, tid, rs, rq, stm, sti);
}

// ---------------------------------------------------------------------------
// Head: y = sigmoid(fc2(fc1(out2))). One wave per (b,t); lane j computes fc1
// output j, then butterfly-reduce the fc2 dot.
// ---------------------------------------------------------------------------
__global__ __launch_bounds__(256) void final_kernel(
    const float* __restrict__ out2, const float* __restrict__ fc1w,
    const float* __restrict__ fc1b, const float* __restrict__ fc2w,
    const float* __restrict__ fc2b, float* __restrict__ out, int T)
{
    int wid = threadIdx.x >> 6, lane = threadIdx.x & 63;
    int bt = blockIdx.x * 4 + wid;

    const float* o2 = out2 + (size_t)bt * 64;
    float acc = fc1b[lane];
    const float* wr = fc1w + (size_t)lane * 64;
#pragma unroll
    for (int k = 0; k < 64; k++) acc += o2[k] * wr[k];

    float p = acc * fc2w[lane];
#pragma unroll
    for (int m = 32; m >= 1; m >>= 1) p += __shfl_xor(p, m);

    if (lane == 0) out[bt] = sigmoidf_(p + fc2b[0]);
}

// ---------------------------------------------------------------------------
extern "C" void kernel_launch(void* const* d_in, const int* in_sizes, int n_in,
                              void* d_out, int out_size, void* d_ws, size_t ws_size,
                              hipStream_t stream)
{
    const float* data  = (const float*)d_in[0];
    const float* h01   = (const float*)d_in[1];
    const float* c01   = (const float*)d_in[2];
    const float* h02   = (const float*)d_in[3];
    const float* c02   = (const float*)d_in[4];
    const float* Wih0  = (const float*)d_in[5];
    const float* Wih12 = (const float*)d_in[6];
    const float* l1Whh = (const float*)d_in[7];
    const float* l1b   = (const float*)d_in[8];
    const float* l2Wih = (const float*)d_in[9];
    const float* l2Whh = (const float*)d_in[10];
    const float* l2b   = (const float*)d_in[11];
    const float* cw1 = (const float*)d_in[12]; const float* cb1 = (const float*)d_in[13];
    const float* cw2 = (const float*)d_in[14]; const float* cb2 = (const float*)d_in[15];
    const float* cw3 = (const float*)d_in[16]; const float* cb3 = (const float*)d_in[17];
    const float* cw4 = (const float*)d_in[18]; const float* cb4 = (const float*)d_in[19];
    const float* fc1w = (const float*)d_in[20]; const float* fc1b = (const float*)d_in[21];
    const float* fc2w = (const float*)d_in[22]; const float* fc2b = (const float*)d_in[23];
    float* out = (float*)d_out;

    const int T = in_sizes[0] / (2 * 40);   // 4096
    const int B = 2;

    float* ws   = (float*)d_ws;
    float* xg   = ws;                                // B*T*256  (8 MB)
    float* seqA = xg   + (size_t)B * T * 256;        // B*T*64   (2 MB)
    float* seqB = seqA + (size_t)B * T * 64;         // B*T*64   (2 MB)
    float* Hc   = seqB + (size_t)B * T * 64;         // B*3*T
    float* bufA = Hc   + (size_t)B * 3 * T;          // B*5*T
    float* bufB = bufA + (size_t)B * 5 * T;          // B*5*T
    float* gate = bufB + (size_t)B * 5 * T;          // B*T

    const int GH = 256 * 64;   // Whh / Wih layer stride
    dim3 pg(B * (T / 16)), pb(256);

    // ---- LSTM1 (3 layers) ----
    proj_kernel<<<pg, pb, 0, stream>>>(data, Wih0, l1b, nullptr, xg, 40, T);
    scan_kernel<<<2, 256, 0, stream>>>(xg, l1Whh, h01, c01, seqA, T);
    proj_kernel<<<pg, pb, 0, stream>>>(seqA, Wih12, l1b + 256, nullptr, xg, 64, T);
    scan_kernel<<<2, 256, 0, stream>>>(xg, l1Whh + GH, h01 + 128, c01 + 128, seqB, T);
    proj_kernel<<<pg, pb, 0, stream>>>(seqB, Wih12 + GH, l1b + 512, nullptr, xg, 64, T);
    scan_kernel<<<2, 256, 0, stream>>>(xg, l1Whh + 2 * GH, h01 + 256, c01 + 256, seqA, T);

    // ---- temporal-attention gate ----
    stats_kernel<<<(2 * T) / 4, 256, 0, stream>>>(seqA, Hc, T);
    middle_kernel<<<1, 1024, 0, stream>>>(Hc, cw1, cb1, cw2, cb2, cw3, cb3, cw4, cb4,
                                          bufA, bufB, gate, T);

    // ---- LSTM2 (3 layers); gate folded into first projection ----
    proj_kernel<<<pg, pb, 0, stream>>>(seqA, l2Wih, l2b, gate, xg, 64, T);
    scan_kernel<<<2, 256, 0, stream>>>(xg, l2Whh, h02, c02, seqB, T);
    proj_kernel<<<pg, pb, 0, stream>>>(seqB, l2Wih + GH, l2b + 256, nullptr, xg, 64, T);
    scan_kernel<<<2, 256, 0, stream>>>(xg, l2Whh + GH, h02 + 128, c02 + 128, seqA, T);
    proj_kernel<<<pg, pb, 0, stream>>>(seqA, l2Wih + 2 * GH, l2b + 512, nullptr, xg, 64, T);
    scan_kernel<<<2, 256, 0, stream>>>(xg, l2Whh + 2 * GH, h02 + 256, c02 + 256, seqB, T);

    // ---- head ----
    final_kernel<<<(2 * T) / 4, 256, 0, stream>>>(seqB, fc1w, fc1b, fc2w, fc2b, out, T);
}

// Round 2
// 14647.807 us; speedup vs baseline: 1.6023x; 1.6023x over previous
//
#include <hip/hip_runtime.h>
#include <hip/hip_bf16.h>
#include <cstdint>
#include <cstddef>

#define DEV __device__ __forceinline__

DEV float sigmoidf_(float x) { return 1.0f / (1.0f + __expf(-x)); }
DEV float tanhf_(float x) {
    float e = __expf(2.0f * x);
    return 1.0f - 2.0f / (e + 1.0f);
}

// LDS-only barrier: does NOT drain vmcnt, so global prefetch loads / Hout
// stores stay in flight across steps (plain __syncthreads would emit
// s_waitcnt vmcnt(0) and serialize on HBM latency every step).
#define LDS_BARRIER() asm volatile("s_waitcnt lgkmcnt(0)\n\ts_barrier" ::: "memory")

// ---------------------------------------------------------------------------
// Input projection: xg[b,t,g] = bias[g] + sum_i (x[b,t,i] + gate?[b,t]) * Wih[g,i]
// ---------------------------------------------------------------------------
__global__ __launch_bounds__(256) void proj_kernel(
    const float* __restrict__ x, const float* __restrict__ Wih,
    const float* __restrict__ bias, const float* __restrict__ gate,
    float* __restrict__ xg, int D, int T)
{
    __shared__ float xS[16 * 64];
    int tb = T / 16;
    int b  = blockIdx.x / tb;
    int t0 = (blockIdx.x % tb) * 16;
    int tid = threadIdx.x;

    int n = 16 * D;
    for (int e = tid; e < n; e += 256) {
        int t = e / D;
        int i = e - t * D;
        float v = x[((size_t)(b * T + t0 + t)) * D + i];
        if (gate) v += gate[b * T + t0 + t];
        xS[t * D + i] = v;
    }
    __syncthreads();

    int g = tid;
    float acc[16];
    float bg = bias[g];
#pragma unroll
    for (int t = 0; t < 16; t++) acc[t] = bg;

    const float* wr = Wih + (size_t)g * D;
    for (int i = 0; i < D; i++) {
        float w = wr[i];
#pragma unroll
        for (int t = 0; t < 16; t++) acc[t] += xS[t * D + i] * w;
    }

    float* og = xg + ((size_t)(b * T + t0)) * 256 + g;
#pragma unroll
    for (int t = 0; t < 16; t++) og[(size_t)t * 256] = acc[t];
}

// ---------------------------------------------------------------------------
// Persistent LSTM scan, one block per batch element, 256 threads.
// Lane mapping: wave w, lane l -> gate q = l>>4, unit u = 16*w + (l&15),
// Whh row r = 64*q + u. All four gates of unit u live in the SAME wave, so
// the gate combine is 4 in-wave shuffles (no barrier). Only the h broadcast
// needs a barrier; hS is double-buffered so one LDS-only barrier per step.
// c is replicated across the 4 gate lanes of each unit (identical inputs).
// ---------------------------------------------------------------------------
__global__ __launch_bounds__(256) void scan_kernel(
    const float* __restrict__ xg, const float* __restrict__ Whh,
    const float* __restrict__ h0, const float* __restrict__ c0,
    float* __restrict__ Hout, int T)
{
    __shared__ float hb0[64];
    __shared__ float hb1[64];
    int b = blockIdx.x;
    int tid = threadIdx.x;
    int w = tid >> 6, l = tid & 63;
    int q = l >> 4, u16 = l & 15;
    int u = 16 * w + u16;
    int r = 64 * q + u;

    float4 w4[16];
    const float4* wp = (const float4*)(Whh + (size_t)r * 64);
#pragma unroll
    for (int k = 0; k < 16; k++) w4[k] = wp[k];

    float c = c0[b * 64 + u];
    if (tid < 64) hb0[tid] = h0[b * 64 + tid];
    __syncthreads();

    const float* xp = xg + (size_t)b * T * 256 + r;
    float xb[4];
#pragma unroll
    for (int k = 0; k < 4; k++) xb[k] = xp[(size_t)k * 256];

    float* hout = Hout + (size_t)b * T * 64 + u;

    for (int t = 0; t < T; t += 4) {
#pragma unroll
        for (int k = 0; k < 4; k++) {
            // prefetch x for step t+4+k (clamped; tail reads are unused)
            int tp = t + 4 + k; if (tp > T - 1) tp = T - 1;
            float xn = xp[(size_t)tp * 256];

            const float4* hv = (const float4*)((k & 1) ? hb1 : hb0);
            float* hN = (k & 1) ? hb0 : hb1;

            float a0 = xb[k], a1 = 0.f, a2 = 0.f, a3 = 0.f;
#pragma unroll
            for (int j = 0; j < 16; j++) {
                float4 h4 = hv[j];
                float4 ww = w4[j];
                a0 += h4.x * ww.x;
                a1 += h4.y * ww.y;
                a2 += h4.z * ww.z;
                a3 += h4.w * ww.w;
            }
            float A = (a0 + a1) + (a2 + a3);

            // gather the 4 gate pre-activations of unit u (same wave)
            float gi = __shfl(A, u16);
            float gf = __shfl(A, u16 + 16);
            float gg = __shfl(A, u16 + 32);
            float go = __shfl(A, u16 + 48);

            c = sigmoidf_(gf) * c + sigmoidf_(gi) * tanhf_(gg);
            float h = sigmoidf_(go) * tanhf_(c);

            if (q == 0) {
                hN[u] = h;
                hout[(size_t)(t + k) * 64] = h;
            }
            xb[k] = xn;
            LDS_BARRIER();
        }
    }
}

// ---------------------------------------------------------------------------
// Hc[b, {max,mean,std(ddof=1)}, t] over hidden dim (64). One wave per (b,t).
// ---------------------------------------------------------------------------
__global__ __launch_bounds__(256) void stats_kernel(
    const float* __restrict__ H, float* __restrict__ Hc, int T)
{
    int wid = threadIdx.x >> 6, lane = threadIdx.x & 63;
    int bt = blockIdx.x * 4 + wid;
    int b = bt / T, t = bt - b * T;

    float x = H[(size_t)bt * 64 + lane];
    float mx = x, sm = x;
#pragma unroll
    for (int m = 32; m >= 1; m >>= 1) {
        mx = fmaxf(mx, __shfl_xor(mx, m));
        sm += __shfl_xor(sm, m);
    }
    float mean = sm * (1.0f / 64.0f);
    float d = x - mean;
    float ss = d * d;
#pragma unroll
    for (int m = 32; m >= 1; m >>= 1) ss += __shfl_xor(ss, m);
    float sd = sqrtf(ss * (1.0f / 63.0f));

    if (lane == 0) {
        float* o = Hc + (size_t)b * 3 * T;
        o[0 * T + t] = mx;
        o[1 * T + t] = mean;
        o[2 * T + t] = sd;
    }
}

// ---------------------------------------------------------------------------
// Middle conv/BN chain, single workgroup (1024 threads).
// ---------------------------------------------------------------------------
template <int CIN, int COUT, int MODE>
DEV void conv_bn_stage(const float* __restrict__ in, const float* __restrict__ w,
                       const float* __restrict__ bias, float* __restrict__ out,
                       float* __restrict__ gate, int T, int tid,
                       float* rs, float* rq, float* stm, float* sti)
{
    float lsum[COUT], lss[COUT];
#pragma unroll
    for (int oc = 0; oc < COUT; oc++) { lsum[oc] = 0.f; lss[oc] = 0.f; }

    for (int k = 0; k < 8; k++) {
        int p = tid + k * 1024;
        int b = p / T;
        int t = p - b * T;
        float acc[COUT];
#pragma unroll
        for (int oc = 0; oc < COUT; oc++) acc[oc] = bias[oc];
#pragma unroll
        for (int ic = 0; ic < CIN; ic++) {
            const float* row = in + ((size_t)b * CIN + ic) * T;
            float xv[11];
#pragma unroll
            for (int kk = 0; kk < 11; kk++) {
                int tt = t + kk - 5;
                xv[kk] = (tt >= 0 && tt < T) ? row[tt] : 0.f;
            }
#pragma unroll
            for (int oc = 0; oc < COUT; oc++) {
                const float* wr = w + ((size_t)oc * CIN + ic) * 11;
#pragma unroll
                for (int kk = 0; kk < 11; kk++) acc[oc] += xv[kk] * wr[kk];
            }
        }
#pragma unroll
        for (int oc = 0; oc < COUT; oc++) {
            out[((size_t)b * COUT + oc) * T + t] = acc[oc];
            lsum[oc] += acc[oc];
            lss[oc] += acc[oc] * acc[oc];
        }
    }
    __syncthreads();

    int lane = tid & 63, wid = tid >> 6;
#pragma unroll
    for (int oc = 0; oc < COUT; oc++) {
        float s = lsum[oc], qq = lss[oc];
#pragma unroll
        for (int m = 32; m >= 1; m >>= 1) {
            s += __shfl_xor(s, m);
            qq += __shfl_xor(qq, m);
        }
        if (lane == 0) { rs[wid] = s; rq[wid] = qq; }
        __syncthreads();
        if (tid == 0) {
            float S = 0.f, Q = 0.f;
            for (int i = 0; i < 16; i++) { S += rs[i]; Q += rq[i]; }
            float m_ = S / (float)(2 * T);
            float v = Q / (float)(2 * T) - m_ * m_;
            stm[oc] = m_;
            sti[oc] = rsqrtf(v + 1e-5f);
        }
        __syncthreads();
    }

    for (int k = 0; k < 8; k++) {
        int p = tid + k * 1024;
        int b = p / T;
        int t = p - b * T;
#pragma unroll
        for (int oc = 0; oc < COUT; oc++) {
            size_t idx = ((size_t)b * COUT + oc) * T + t;
            float v = (out[idx] - stm[oc]) * sti[oc];
            if (MODE == 0) out[idx] = fmaxf(v, 0.f);
            else           gate[p] = sigmoidf_(v);
        }
    }
    __syncthreads();
}

__global__ __launch_bounds__(1024) void middle_kernel(
    const float* __restrict__ Hc,
    const float* __restrict__ w1, const float* __restrict__ b1,
    const float* __restrict__ w2, const float* __restrict__ b2,
    const float* __restrict__ w3, const float* __restrict__ b3,
    const float* __restrict__ w4, const float* __restrict__ b4,
    float* __restrict__ bufA, float* __restrict__ bufB,
    float* __restrict__ gate, int T)
{
    __shared__ float rs[16], rq[16], stm[8], sti[8];
    int tid = threadIdx.x;
    conv_bn_stage<3, 3, 0>(Hc,   w1, b1, bufA, nullptr, T, tid, rs, rq, stm, sti);
    conv_bn_stage<3, 5, 0>(bufA, w2, b2, bufB, nullptr, T, tid, rs, rq, stm, sti);
    conv_bn_stage<5, 5, 0>(bufB, w3, b3, bufA, nullptr, T, tid, rs, rq, stm, sti);
    conv_bn_stage<5, 1, 1>(bufA, w4, b4, bufB, gate,    T, tid, rs, rq, stm, sti);
}

// ---------------------------------------------------------------------------
// Head: y = sigmoid(fc2(fc1(out2))). One wave per (b,t).
// ---------------------------------------------------------------------------
__global__ __launch_bounds__(256) void final_kernel(
    const float* __restrict__ out2, const float* __restrict__ fc1w,
    const float* __restrict__ fc1b, const float* __restrict__ fc2w,
    const float* __restrict__ fc2b, float* __restrict__ out, int T)
{
    int wid = threadIdx.x >> 6, lane = threadIdx.x & 63;
    int bt = blockIdx.x * 4 + wid;

    const float* o2 = out2 + (size_t)bt * 64;
    float acc = fc1b[lane];
    const float* wr = fc1w + (size_t)lane * 64;
#pragma unroll
    for (int k = 0; k < 64; k++) acc += o2[k] * wr[k];

    float p = acc * fc2w[lane];
#pragma unroll
    for (int m = 32; m >= 1; m >>= 1) p += __shfl_xor(p, m);

    if (lane == 0) out[bt] = sigmoidf_(p + fc2b[0]);
}

// ---------------------------------------------------------------------------
extern "C" void kernel_launch(void* const* d_in, const int* in_sizes, int n_in,
                              void* d_out, int out_size, void* d_ws, size_t ws_size,
                              hipStream_t stream)
{
    const float* data  = (const float*)d_in[0];
    const float* h01   = (const float*)d_in[1];
    const float* c01   = (const float*)d_in[2];
    const float* h02   = (const float*)d_in[3];
    const float* c02   = (const float*)d_in[4];
    const float* Wih0  = (const float*)d_in[5];
    const float* Wih12 = (const float*)d_in[6];
    const float* l1Whh = (const float*)d_in[7];
    const float* l1b   = (const float*)d_in[8];
    const float* l2Wih = (const float*)d_in[9];
    const float* l2Whh = (const float*)d_in[10];
    const float* l2b   = (const float*)d_in[11];
    const float* cw1 = (const float*)d_in[12]; const float* cb1 = (const float*)d_in[13];
    const float* cw2 = (const float*)d_in[14]; const float* cb2 = (const float*)d_in[15];
    const float* cw3 = (const float*)d_in[16]; const float* cb3 = (const float*)d_in[17];
    const float* cw4 = (const float*)d_in[18]; const float* cb4 = (const float*)d_in[19];
    const float* fc1w = (const float*)d_in[20]; const float* fc1b = (const float*)d_in[21];
    const float* fc2w = (const float*)d_in[22]; const float* fc2b = (const float*)d_in[23];
    float* out = (float*)d_out;

    const int T = in_sizes[0] / (2 * 40);   // 4096
    const int B = 2;

    float* ws   = (float*)d_ws;
    float* xg   = ws;                                // B*T*256
    float* seqA = xg   + (size_t)B * T * 256;        // B*T*64
    float* seqB = seqA + (size_t)B * T * 64;         // B*T*64
    float* Hc   = seqB + (size_t)B * T * 64;         // B*3*T
    float* bufA = Hc   + (size_t)B * 3 * T;          // B*5*T
    float* bufB = bufA + (size_t)B * 5 * T;          // B*5*T
    float* gate = bufB + (size_t)B * 5 * T;          // B*T

    const int GH = 256 * 64;
    dim3 pg(B * (T / 16)), pb(256);

    // ---- LSTM1 (3 layers) ----
    proj_kernel<<<pg, pb, 0, stream>>>(data, Wih0, l1b, nullptr, xg, 40, T);
    scan_kernel<<<2, 256, 0, stream>>>(xg, l1Whh, h01, c01, seqA, T);
    proj_kernel<<<pg, pb, 0, stream>>>(seqA, Wih12, l1b + 256, nullptr, xg, 64, T);
    scan_kernel<<<2, 256, 0, stream>>>(xg, l1Whh + GH, h01 + 128, c01 + 128, seqB, T);
    proj_kernel<<<pg, pb, 0, stream>>>(seqB, Wih12 + GH, l1b + 512, nullptr, xg, 64, T);
    scan_kernel<<<2, 256, 0, stream>>>(xg, l1Whh + 2 * GH, h01 + 256, c01 + 256, seqA, T);

    // ---- temporal-attention gate ----
    stats_kernel<<<(2 * T) / 4, 256, 0, stream>>>(seqA, Hc, T);
    middle_kernel<<<1, 1024, 0, stream>>>(Hc, cw1, cb1, cw2, cb2, cw3, cb3, cw4, cb4,
                                          bufA, bufB, gate, T);

    // ---- LSTM2 (3 layers); gate folded into first projection ----
    proj_kernel<<<pg, pb, 0, stream>>>(seqA, l2Wih, l2b, gate, xg, 64, T);
    scan_kernel<<<2, 256, 0, stream>>>(xg, l2Whh, h02, c02, seqB, T);
    proj_kernel<<<pg, pb, 0, stream>>>(seqB, l2Wih + GH, l2b + 256, nullptr, xg, 64, T);
    scan_kernel<<<2, 256, 0, stream>>>(xg, l2Whh + GH, h02 + 128, c02 + 128, seqA, T);
    proj_kernel<<<pg, pb, 0, stream>>>(seqA, l2Wih + 2 * GH, l2b + 512, nullptr, xg, 64, T);
    scan_kernel<<<2, 256, 0, stream>>>(xg, l2Whh + 2 * GH, h02 + 256, c02 + 256, seqB, T);

    // ---- head ----
    final_kernel<<<(2 * T) / 4, 256, 0, stream>>>(seqB, fc1w, fc1b, fc2w, fc2b, out, T);
}